// Round 16
// baseline (43.224 us; speedup 1.0000x reference)
//
#include <hip/hip_runtime.h>
#include <math.h>

#define NEAR_T   2.0f
#define FAR_T    6.0f
#define EPS_W_C  1e-5f
#define EPS_T_C  1e-10f
#define FAR_DIST 1e10f
#define L2E      1.4426950408889634f
#define INV63    (1.0f / 63.0f)

typedef float v2f __attribute__((ext_vector_type(2)));

__device__ __forceinline__ float tval(int i) {
    return NEAR_T + (FAR_T - NEAR_T) * ((float)i * INV63);
}
__device__ __forceinline__ float rcp_fast(float x) { return __builtin_amdgcn_rcpf(x); }
__device__ __forceinline__ float exp2_f(float x)  { return __builtin_amdgcn_exp2f(x); }
__device__ __forceinline__ float log2_f(float x)  { return __builtin_amdgcn_logf(x); }
__device__ __forceinline__ v2f fma2(v2f a, v2f b, v2f c) {
    return __builtin_elementwise_fma(a, b, c);
}
__device__ __forceinline__ float shfx1(float v) { return __shfl_xor(v, 1); }

// safe base-2 softplus (two-path log2(1+e)): preserves sigma down to ~1e-13,
// REQUIRED where dist=1e10 can saturate alpha from a tiny sigma (R2 failure).
__device__ __forceinline__ float softplus2_safe(float xp) {
    const float e = exp2_f(-fabsf(xp));
    const float big   = log2_f(1.0f + e);
    const float small = e * (1.4426950f - e * (0.72134751f - e * 0.48089835f));
    return fmaxf(xp, 0.0f) + ((e > 0.0078125f) ? big : small);
}

struct FieldV { float sig; float c2; v2f c01; };

__device__ __forceinline__ FieldV eval_fast(float t, v2f A0, v2f A1, v2f B0, v2f B1) {
    const v2f tt = {t, t};
    const v2f a = fma2(tt, A1, A0);          // (dd', c2-arg)
    const v2f b = fma2(tt, B1, B0);          // (c0-arg, c1-arg)
    const float ea  = exp2_f(-fabsf(a.x));
    const float ec  = exp2_f(-a.y);
    const float eb0 = exp2_f(-b.x);
    const float eb1 = exp2_f(-b.y);
    const v2f pa = (v2f){ea, ec} + (v2f){1.0f, 1.0f};
    const v2f pb = (v2f){eb0, eb1} + (v2f){1.0f, 1.0f};
    FieldV r;
    r.sig = fmaxf(a.x, 0.0f) + log2_f(pa.x);
    r.c2  = rcp_fast(pa.y);
    r.c01 = (v2f){rcp_fast(pb.x), rcp_fast(pb.y)};
    return r;
}

// TWO THREADS PER RAY: lane A (even) = coarse samples 0-31 + merged elements
// 0..63; lane B (odd) = samples 32-63 + merged elements 64..127 via merge-path.
// Optical-depth linearity: global = A_part + exp2(-S_A) * B_local.
__global__ __launch_bounds__(256, 4)
void volrender_tpr2(const float* __restrict__ ro_g,
                    const float* __restrict__ rd_g,
                    const float* __restrict__ Wd_g,
                    const float* __restrict__ Wc_g,
                    float* __restrict__ out, int N) {
    __shared__ float s_cdf[64][128];   // [row][col]; 128%32==0 -> bank = col%32

    const int tid = threadIdx.x;
    const int col = tid >> 1;
    const int isB = tid & 1;
    int ray = blockIdx.x * 128 + col;
    if (ray >= N) ray = N - 1;  // duplicate pair computes identical values

    const float ox = ro_g[ray * 3 + 0], oy = ro_g[ray * 3 + 1], oz = ro_g[ray * 3 + 2];
    const float dx = rd_g[ray * 3 + 0], dy = rd_g[ray * 3 + 1], dz = rd_g[ray * 3 + 2];
    const float wd0 = Wd_g[0], wd1 = Wd_g[1], wd2 = Wd_g[2];
    float wcm[9];
#pragma unroll
    for (int k = 0; k < 9; ++k) wcm[k] = Wc_g[k];

    const v2f A0 = { (ox * wd0 + oy * wd1 + oz * wd2) * L2E,
                     (ox * wcm[2] + oy * wcm[5] + oz * wcm[8]) * L2E };
    const v2f A1 = { (dx * wd0 + dy * wd1 + dz * wd2) * L2E,
                     (dx * wcm[2] + dy * wcm[5] + dz * wcm[8]) * L2E };
    const v2f B0 = { (ox * wcm[0] + oy * wcm[3] + oz * wcm[6]) * L2E,
                     (ox * wcm[1] + oy * wcm[4] + oz * wcm[7]) * L2E };
    const v2f B1 = { (dx * wcm[0] + dy * wcm[3] + dz * wcm[6]) * L2E,
                     (dx * wcm[1] + dy * wcm[4] + dz * wcm[7]) * L2E };

    const float W = (FAR_T - NEAR_T) * INV63;
    const float TMAX = tval(63);

    const long Nl = N;
    float* out_rgb  = out;
    float* out_dep  = out + 3 * Nl;
    float* out_acc  = out + 4 * Nl;
    float* out_frgb = out + 5 * Nl;
    float* out_fdep = out + 8 * Nl;
    float* out_facc = out + 9 * Nl;

    // ---------------- pass 1: 32 samples per lane ----------------
    const float tstart = fmaf(isB ? 32.0f : 0.0f, W, NEAR_T);
    float q  = exp2_f(fmaf(tstart, A1.x, A0.x));
    float z2 = exp2_f(-fmaf(tstart, A1.y, A0.y));
    float z0 = exp2_f(-fmaf(tstart, B1.x, B0.x));
    float z1 = exp2_f(-fmaf(tstart, B1.y, B0.y));
    const float Kq  = exp2_f(A1.x * W);
    const float Kz2 = exp2_f(-A1.y * W);
    const float Kz0 = exp2_f(-B1.x * W);
    const float Kz1 = exp2_f(-B1.y * W);

    float S1 = 0.0f, Tp1 = 1.0f;
    float acc = 0.0f, dep = 0.0f, r2 = 0.0f, total = 0.0f, sumw = 0.0f;
    v2f r01 = {0.0f, 0.0f};
    float t = tstart;
    const int rowbase = isB ? 32 : 0;
#pragma unroll 4
    for (int k = 0; k < 31; ++k) {
        const float sig = log2_f(1.0f + q);
        const float c0 = rcp_fast(1.0f + z0);
        const float c1 = rcp_fast(1.0f + z1);
        const float c2 = rcp_fast(1.0f + z2);
        S1 = fmaf(sig, W, S1);
        const float T = exp2_f(-S1);
        const float w = Tp1 - T; Tp1 = T;
        acc += w; dep = fmaf(w, t, dep);
        r01 = fma2((v2f){w, w}, (v2f){c0, c1}, r01);
        r2 = fmaf(w, c2, r2);
        total += w + EPS_W_C;   // A's global prefix
        sumw  += w;             // B's raw prefix
        s_cdf[rowbase + k][col] = isB ? sumw : total;
        t += W;
        q *= Kq; z0 *= Kz0; z1 *= Kz1; z2 *= Kz2;
    }
    {   // k=31: A -> sample 31 (dist W); B -> sample 63 (FAR, safe softplus)
        const float sig = isB ? softplus2_safe(fmaf(t, A1.x, A0.x)) : log2_f(1.0f + q);
        const float c0 = rcp_fast(1.0f + z0);
        const float c1 = rcp_fast(1.0f + z1);
        const float c2 = rcp_fast(1.0f + z2);
        const float dist = isB ? FAR_DIST : W;
        S1 = fmaf(sig, dist, S1);
        const float T = exp2_f(-S1);
        const float w = Tp1 - T; Tp1 = T;
        acc += w; dep = fmaf(w, t, dep);
        r01 = fma2((v2f){w, w}, (v2f){c0, c1}, r01);
        r2 = fmaf(w, c2, r2);
        total += w + EPS_W_C;
        sumw += w;
        s_cdf[rowbase + 31][col] = isB ? sumw : total;
    }

    // exchange: B gets A's end-transmittance and cdf end
    const float TA   = shfx1(Tp1);
    const float cdfA = shfx1(total);
    float total_g;
    {
        const float tgB = fmaf(TA, sumw, cdfA) + 32.0f * EPS_W_C;  // valid on B
        const float tgA = shfx1(tgB);
        total_g = isB ? tgB : tgA;
    }
    {   // coarse combine on A: global = A + Tp1 * B_local
        const float bacc = shfx1(acc), bdep = shfx1(dep), br2 = shfx1(r2);
        const float br0 = shfx1(r01.x), br1 = shfx1(r01.y);
        if (!isB) {
            const float ga = fmaf(Tp1, bacc, acc);
            const float gd = fmaf(Tp1, bdep, dep);
            const float g0 = fmaf(Tp1, br0, r01.x);
            const float g1 = fmaf(Tp1, br1, r01.y);
            const float g2 = fmaf(Tp1, br2, r2);
            const float bg = 1.0f - ga;
            out_rgb[ray * 3 + 0] = g0 + bg;
            out_rgb[ray * 3 + 1] = g1 + bg;
            out_rgb[ray * 3 + 2] = g2 + bg;
            out_dep[ray] = gd;
            out_acc[ray] = ga;
        }
    }
    if (isB) {  // fix rows 32..63: global = cdfA + TA*raw + eps*(k+1)
        float ebase = cdfA + EPS_W_C;
#pragma unroll 4
        for (int k = 0; k < 32; ++k) {
            const float raw = s_cdf[32 + k][col];
            s_cdf[32 + k][col] = fmaf(TA, raw, ebase);
            ebase += EPS_W_C;
        }
    }
    __syncthreads();
    const float inv_total = rcp_fast(total_g);

    // ---------------- pass 2: 64 merged elements per lane ----------------
    float Sf = 0.0f, Tpf = 1.0f;
    float facc = 0.0f, fdep = 0.0f, fr2 = 0.0f;
    v2f fr01 = {0.0f, 0.0f};
    float lo, hi, bin0, bin1, binw, jf, Snext;
    int i;
    float pt, ps, pc2; v2f pc01;

    if (!isB) {  // peel element 0 (grid 0)
        const FieldV F = eval_fast(NEAR_T, A0, A1, B0, B1);
        pt = NEAR_T; ps = F.sig; pc01 = F.c01; pc2 = F.c2;
        i = 1; jf = 0.0f;
        lo = 0.0f; hi = s_cdf[0][col] * inv_total;
        bin0 = NEAR_T; bin1 = NEAR_T + W; binw = bin1 - bin0;
        Snext = s_cdf[1][col];
    } else {
        // merge-path: smallest i0 in [1,64] with i0 + #{j: u_j < cdf_{i0-1}} >= 64
        int loI = 1, hiI = 64;
        while (loI < hiI) {
            const int mid = (loI + hiI) >> 1;
            const float c = s_cdf[mid - 1][col] * inv_total;
            int k = (int)(c * 63.0f);
            k = min(max(k, 0), 64);
#pragma unroll
            for (int f = 0; f < 3; ++f) if (k > 0 && (float)(k - 1) * INV63 >= c) --k;
#pragma unroll
            for (int f = 0; f < 3; ++f) if (k < 64 && (float)k * INV63 < c) ++k;
            if (mid + k >= 64) hiI = mid; else loI = mid + 1;
        }
        const int i0 = loI;
        jf = (float)(64 - i0);
        lo = (i0 >= 2) ? s_cdf[i0 - 2][col] * inv_total : 0.0f;
        hi = s_cdf[i0 - 1][col] * inv_total;
        bin1 = fminf(fmaf((float)i0, W, NEAR_T), TMAX);
        bin0 = fminf(fmaf((float)(i0 - 1), W, NEAR_T), TMAX);
        binw = bin1 - bin0;
        i = i0;
        Snext = s_cdf[min(i0, 63)][col];
        // peel merged element 64 (becomes the lag; composited by first loop iter)
        float dnm = hi - lo; dnm = (dnm < EPS_W_C) ? 1.0f : dnm;
        const float u = jf * INV63;
        const float ts = fmaf((u - lo) * rcp_fast(dnm), binw, bin0);
        const bool samp = (jf < 63.5f) && ((i >= 64) || (u < hi));
        const float tm = samp ? ts : bin1;
        const FieldV F = eval_fast(tm, A0, A1, B0, B1);
        if (samp) { jf += 1.0f; }
        else {
            lo = hi; hi = Snext * inv_total;
            bin0 = bin1; bin1 = fminf(bin1 + W, TMAX); binw = bin1 - bin0;
            ++i; Snext = s_cdf[min(i, 63)][col];
        }
        pt = tm; ps = F.sig; pc01 = F.c01; pc2 = F.c2;
    }

#pragma unroll 4
    for (int e = 0; e < 63; ++e) {
        float dnm = hi - lo; dnm = (dnm < EPS_W_C) ? 1.0f : dnm;
        const float u = jf * INV63;
        const float ts = fmaf((u - lo) * rcp_fast(dnm), binw, bin0);
        const bool samp = (jf < 63.5f) && ((i >= 64) || (u < hi));
        const float tm = samp ? ts : bin1;
        const FieldV F = eval_fast(tm, A0, A1, B0, B1);
        Sf = fmaf(ps, tm - pt, Sf);
        const float T = exp2_f(-Sf);
        const float wf = Tpf - T; Tpf = T;
        facc += wf; fdep = fmaf(wf, pt, fdep);
        fr01 = fma2((v2f){wf, wf}, pc01, fr01);
        fr2 = fmaf(wf, pc2, fr2);
        if (samp) { jf += 1.0f; }
        else {
            lo = hi; hi = Snext * inv_total;
            bin0 = bin1; bin1 = fminf(bin1 + W, TMAX); binw = bin1 - bin0;
            ++i; Snext = s_cdf[min(i, 63)][col];
        }
        pt = tm; ps = F.sig; pc01 = F.c01; pc2 = F.c2;
    }
    {   // tail: A composites element 63 (dist = t64 - t63); B composites 127 (FAR)
        float dnm = hi - lo; dnm = (dnm < EPS_W_C) ? 1.0f : dnm;
        const float u = jf * INV63;
        const float ts = fmaf((u - lo) * rcp_fast(dnm), binw, bin0);
        const bool samp = (jf < 63.5f) && ((i >= 64) || (u < hi));
        const float tm = samp ? ts : bin1;          // A: t_64; B: unused
        const float sig_safe = softplus2_safe(fmaf(pt, A1.x, A0.x));
        const float ps_e = isB ? sig_safe : ps;
        const float dist = isB ? FAR_DIST : (tm - pt);
        Sf = fmaf(ps_e, dist, Sf);
        const float T = exp2_f(-Sf);
        const float wf = Tpf - T;
        facc += wf; fdep = fmaf(wf, pt, fdep);
        fr01 = fma2((v2f){wf, wf}, pc01, fr01);
        fr2 = fmaf(wf, pc2, fr2);
    }
    {   // fine combine on A: global = A + exp2(-Sf_A) * B_local
        const float TFA = exp2_f(-Sf);              // A: T at element-64 boundary
        const float bfacc = shfx1(facc), bfdep = shfx1(fdep), bfr2 = shfx1(fr2);
        const float bf0 = shfx1(fr01.x), bf1 = shfx1(fr01.y);
        if (!isB) {
            const float ga = fmaf(TFA, bfacc, facc);
            const float gd = fmaf(TFA, bfdep, fdep);
            const float g0 = fmaf(TFA, bf0, fr01.x);
            const float g1 = fmaf(TFA, bf1, fr01.y);
            const float g2 = fmaf(TFA, bfr2, fr2);
            const float bg = 1.0f - ga;
            out_frgb[ray * 3 + 0] = g0 + bg;
            out_frgb[ray * 3 + 1] = g1 + bg;
            out_frgb[ray * 3 + 2] = g2 + bg;
            out_fdep[ray] = gd;
            out_facc[ray] = ga;
        }
    }
}

extern "C" void kernel_launch(void* const* d_in, const int* in_sizes, int n_in,
                              void* d_out, int out_size, void* d_ws, size_t ws_size,
                              hipStream_t stream) {
    const float* ro = (const float*)d_in[0];
    const float* rd = (const float*)d_in[1];
    // d_in[2] exposure_values, d_in[5] appearance_ids: unused by reference
    const float* Wd = (const float*)d_in[3];
    const float* Wc = (const float*)d_in[4];
    float* out = (float*)d_out;

    const int N = in_sizes[0] / 3;
    const int grid = (2 * N + 255) / 256;
    volrender_tpr2<<<grid, 256, 0, stream>>>(ro, rd, Wd, Wc, out, N);
}

// Round 17
// 43.050 us; speedup vs baseline: 1.0041x; 1.0041x over previous
//
#include <hip/hip_runtime.h>
#include <math.h>

#define NEAR_T   2.0f
#define FAR_T    6.0f
#define EPS_W_C  1e-5f
#define EPS_T_C  1e-10f
#define FAR_DIST 1e10f
#define L2E      1.4426950408889634f
#define INV63    (1.0f / 63.0f)

typedef float v2f __attribute__((ext_vector_type(2)));

__device__ __forceinline__ float tval(int i) {
    return NEAR_T + (FAR_T - NEAR_T) * ((float)i * INV63);
}
__device__ __forceinline__ float rcp_fast(float x) { return __builtin_amdgcn_rcpf(x); }
__device__ __forceinline__ float exp2_f(float x)  { return __builtin_amdgcn_exp2f(x); }
__device__ __forceinline__ float log2_f(float x)  { return __builtin_amdgcn_logf(x); }
__device__ __forceinline__ v2f fma2(v2f a, v2f b, v2f c) {
    return __builtin_elementwise_fma(a, b, c);
}
__device__ __forceinline__ float shfx1(float v) { return __shfl_xor(v, 1); }

// safe base-2 softplus (two-path log2(1+e)): preserves sigma down to ~1e-13,
// REQUIRED where dist=1e10 can saturate alpha from a tiny sigma (R2 failure).
__device__ __forceinline__ float softplus2_safe(float xp) {
    const float e = exp2_f(-fabsf(xp));
    const float big   = log2_f(1.0f + e);
    const float small = e * (1.4426950f - e * (0.72134751f - e * 0.48089835f));
    return fmaxf(xp, 0.0f) + ((e > 0.0078125f) ? big : small);
}

struct FieldV { float sig; float c2; v2f c01; };

__device__ __forceinline__ FieldV eval_fast(float t, v2f A0, v2f A1, v2f B0, v2f B1) {
    const v2f tt = {t, t};
    const v2f a = fma2(tt, A1, A0);          // (dd', c2-arg)
    const v2f b = fma2(tt, B1, B0);          // (c0-arg, c1-arg)
    const float ea  = exp2_f(-fabsf(a.x));
    const float ec  = exp2_f(-a.y);
    const float eb0 = exp2_f(-b.x);
    const float eb1 = exp2_f(-b.y);
    const v2f pa = (v2f){ea, ec} + (v2f){1.0f, 1.0f};
    const v2f pb = (v2f){eb0, eb1} + (v2f){1.0f, 1.0f};
    FieldV r;
    r.sig = fmaxf(a.x, 0.0f) + log2_f(pa.x);
    r.c2  = rcp_fast(pa.y);
    r.c01 = (v2f){rcp_fast(pb.x), rcp_fast(pb.y)};
    return r;
}

// TWO THREADS PER RAY (R16 structure, overhead-trimmed):
//  - no __syncthreads: all LDS is pair-private (same wave), lgkmcnt suffices
//  - fixup loop split across A/B lanes (16 rows each, full lane utilization)
//  - plain launch_bounds (VGPR floats to ~88; (256,4) forced 44 -> remat)
//  - s_cdf rows padded to 129: bank=(row+col)%32 kills pair 2-way aliasing
__global__ __launch_bounds__(256)
void volrender_tpr2(const float* __restrict__ ro_g,
                    const float* __restrict__ rd_g,
                    const float* __restrict__ Wd_g,
                    const float* __restrict__ Wc_g,
                    float* __restrict__ out, int N) {
    __shared__ float s_cdf[64][129];

    const int tid = threadIdx.x;
    const int col = tid >> 1;
    const int isB = tid & 1;
    int ray = blockIdx.x * 128 + col;
    if (ray >= N) ray = N - 1;  // duplicate pair computes identical values

    const float ox = ro_g[ray * 3 + 0], oy = ro_g[ray * 3 + 1], oz = ro_g[ray * 3 + 2];
    const float dx = rd_g[ray * 3 + 0], dy = rd_g[ray * 3 + 1], dz = rd_g[ray * 3 + 2];
    const float wd0 = Wd_g[0], wd1 = Wd_g[1], wd2 = Wd_g[2];
    float wcm[9];
#pragma unroll
    for (int k = 0; k < 9; ++k) wcm[k] = Wc_g[k];

    const v2f A0 = { (ox * wd0 + oy * wd1 + oz * wd2) * L2E,
                     (ox * wcm[2] + oy * wcm[5] + oz * wcm[8]) * L2E };
    const v2f A1 = { (dx * wd0 + dy * wd1 + dz * wd2) * L2E,
                     (dx * wcm[2] + dy * wcm[5] + dz * wcm[8]) * L2E };
    const v2f B0 = { (ox * wcm[0] + oy * wcm[3] + oz * wcm[6]) * L2E,
                     (ox * wcm[1] + oy * wcm[4] + oz * wcm[7]) * L2E };
    const v2f B1 = { (dx * wcm[0] + dy * wcm[3] + dz * wcm[6]) * L2E,
                     (dx * wcm[1] + dy * wcm[4] + dz * wcm[7]) * L2E };

    const float W = (FAR_T - NEAR_T) * INV63;
    const float TMAX = tval(63);

    const long Nl = N;
    float* out_rgb  = out;
    float* out_dep  = out + 3 * Nl;
    float* out_acc  = out + 4 * Nl;
    float* out_frgb = out + 5 * Nl;
    float* out_fdep = out + 8 * Nl;
    float* out_facc = out + 9 * Nl;

    // ---------------- pass 1: 32 samples per lane ----------------
    const float tstart = fmaf(isB ? 32.0f : 0.0f, W, NEAR_T);
    float q  = exp2_f(fmaf(tstart, A1.x, A0.x));
    float z2 = exp2_f(-fmaf(tstart, A1.y, A0.y));
    float z0 = exp2_f(-fmaf(tstart, B1.x, B0.x));
    float z1 = exp2_f(-fmaf(tstart, B1.y, B0.y));
    const float Kq  = exp2_f(A1.x * W);
    const float Kz2 = exp2_f(-A1.y * W);
    const float Kz0 = exp2_f(-B1.x * W);
    const float Kz1 = exp2_f(-B1.y * W);

    float S1 = 0.0f, Tp1 = 1.0f;
    float acc = 0.0f, dep = 0.0f, r2 = 0.0f, total = 0.0f, sumw = 0.0f;
    v2f r01 = {0.0f, 0.0f};
    float t = tstart;
    const int rowbase = isB ? 32 : 0;
#pragma unroll 4
    for (int k = 0; k < 31; ++k) {
        const float sig = log2_f(1.0f + q);
        const float c0 = rcp_fast(1.0f + z0);
        const float c1 = rcp_fast(1.0f + z1);
        const float c2 = rcp_fast(1.0f + z2);
        S1 = fmaf(sig, W, S1);
        const float T = exp2_f(-S1);
        const float w = Tp1 - T; Tp1 = T;
        acc += w; dep = fmaf(w, t, dep);
        r01 = fma2((v2f){w, w}, (v2f){c0, c1}, r01);
        r2 = fmaf(w, c2, r2);
        total += w + EPS_W_C;   // A's global prefix
        sumw  += w;             // B's raw prefix
        s_cdf[rowbase + k][col] = isB ? sumw : total;
        t += W;
        q *= Kq; z0 *= Kz0; z1 *= Kz1; z2 *= Kz2;
    }
    {   // k=31: A -> sample 31 (dist W); B -> sample 63 (FAR, safe softplus)
        const float sig = isB ? softplus2_safe(fmaf(t, A1.x, A0.x)) : log2_f(1.0f + q);
        const float c0 = rcp_fast(1.0f + z0);
        const float c1 = rcp_fast(1.0f + z1);
        const float c2 = rcp_fast(1.0f + z2);
        const float dist = isB ? FAR_DIST : W;
        S1 = fmaf(sig, dist, S1);
        const float T = exp2_f(-S1);
        const float w = Tp1 - T; Tp1 = T;
        acc += w; dep = fmaf(w, t, dep);
        r01 = fma2((v2f){w, w}, (v2f){c0, c1}, r01);
        r2 = fmaf(w, c2, r2);
        total += w + EPS_W_C;
        sumw += w;
        s_cdf[rowbase + 31][col] = isB ? sumw : total;
    }

    // exchange: B gets A's end-transmittance and cdf end
    const float TA   = shfx1(Tp1);
    const float cdfA = shfx1(total);
    float total_g;
    {
        const float tgB = fmaf(TA, sumw, cdfA) + 32.0f * EPS_W_C;  // valid on B
        const float tgA = shfx1(tgB);
        total_g = isB ? tgB : tgA;
    }
    {   // coarse combine on A: global = A + Tp1 * B_local
        const float bacc = shfx1(acc), bdep = shfx1(dep), br2 = shfx1(r2);
        const float br0 = shfx1(r01.x), br1 = shfx1(r01.y);
        if (!isB) {
            const float ga = fmaf(Tp1, bacc, acc);
            const float gd = fmaf(Tp1, bdep, dep);
            const float g0 = fmaf(Tp1, br0, r01.x);
            const float g1 = fmaf(Tp1, br1, r01.y);
            const float g2 = fmaf(Tp1, br2, r2);
            const float bg = 1.0f - ga;
            out_rgb[ray * 3 + 0] = g0 + bg;
            out_rgb[ray * 3 + 1] = g1 + bg;
            out_rgb[ray * 3 + 2] = g2 + bg;
            out_dep[ray] = gd;
            out_acc[ray] = ga;
        }
    }
    {   // fixup rows 32..63, split A:32-47 B:48-63 (full lane utilization):
        // global = cdfA + TA*raw + eps*(row-31). A uses its own Tp1/total;
        // B uses the shuffled copies. Pair-private LDS, same wave -> ordered.
        const float TA_f   = isB ? TA   : Tp1;
        const float cdfA_f = isB ? cdfA : total;
        const int r0 = isB ? 48 : 32;
        float ebase = cdfA_f + (float)(r0 - 31) * EPS_W_C;
#pragma unroll 4
        for (int k = 0; k < 16; ++k) {
            const float raw = s_cdf[r0 + k][col];
            s_cdf[r0 + k][col] = fmaf(TA_f, raw, ebase);
            ebase += EPS_W_C;
        }
    }
    const float inv_total = rcp_fast(total_g);

    // ---------------- pass 2: 64 merged elements per lane ----------------
    float Sf = 0.0f, Tpf = 1.0f;
    float facc = 0.0f, fdep = 0.0f, fr2 = 0.0f;
    v2f fr01 = {0.0f, 0.0f};
    float lo, hi, bin0, bin1, binw, jf, Snext;
    int i;
    float pt, ps, pc2; v2f pc01;

    if (!isB) {  // peel element 0 (grid 0)
        const FieldV F = eval_fast(NEAR_T, A0, A1, B0, B1);
        pt = NEAR_T; ps = F.sig; pc01 = F.c01; pc2 = F.c2;
        i = 1; jf = 0.0f;
        lo = 0.0f; hi = s_cdf[0][col] * inv_total;
        bin0 = NEAR_T; bin1 = NEAR_T + W; binw = bin1 - bin0;
        Snext = s_cdf[1][col];
    } else {
        // merge-path: smallest i0 in [1,64] with i0 + #{j: u_j < cdf_{i0-1}} >= 64
        int loI = 1, hiI = 64;
        while (loI < hiI) {
            const int mid = (loI + hiI) >> 1;
            const float c = s_cdf[mid - 1][col] * inv_total;
            int k = (int)(c * 63.0f);
            k = min(max(k, 0), 64);
#pragma unroll
            for (int f = 0; f < 3; ++f) if (k > 0 && (float)(k - 1) * INV63 >= c) --k;
#pragma unroll
            for (int f = 0; f < 3; ++f) if (k < 64 && (float)k * INV63 < c) ++k;
            if (mid + k >= 64) hiI = mid; else loI = mid + 1;
        }
        const int i0 = loI;
        jf = (float)(64 - i0);
        lo = (i0 >= 2) ? s_cdf[i0 - 2][col] * inv_total : 0.0f;
        hi = s_cdf[i0 - 1][col] * inv_total;
        bin1 = fminf(fmaf((float)i0, W, NEAR_T), TMAX);
        bin0 = fminf(fmaf((float)(i0 - 1), W, NEAR_T), TMAX);
        binw = bin1 - bin0;
        i = i0;
        Snext = s_cdf[min(i0, 63)][col];
        // peel merged element 64 (becomes the lag; composited by first loop iter)
        float dnm = hi - lo; dnm = (dnm < EPS_W_C) ? 1.0f : dnm;
        const float u = jf * INV63;
        const float ts = fmaf((u - lo) * rcp_fast(dnm), binw, bin0);
        const bool samp = (jf < 63.5f) && ((i >= 64) || (u < hi));
        const float tm = samp ? ts : bin1;
        const FieldV F = eval_fast(tm, A0, A1, B0, B1);
        if (samp) { jf += 1.0f; }
        else {
            lo = hi; hi = Snext * inv_total;
            bin0 = bin1; bin1 = fminf(bin1 + W, TMAX); binw = bin1 - bin0;
            ++i; Snext = s_cdf[min(i, 63)][col];
        }
        pt = tm; ps = F.sig; pc01 = F.c01; pc2 = F.c2;
    }

#pragma unroll 4
    for (int e = 0; e < 63; ++e) {
        float dnm = hi - lo; dnm = (dnm < EPS_W_C) ? 1.0f : dnm;
        const float u = jf * INV63;
        const float ts = fmaf((u - lo) * rcp_fast(dnm), binw, bin0);
        const bool samp = (jf < 63.5f) && ((i >= 64) || (u < hi));
        const float tm = samp ? ts : bin1;
        const FieldV F = eval_fast(tm, A0, A1, B0, B1);
        Sf = fmaf(ps, tm - pt, Sf);
        const float T = exp2_f(-Sf);
        const float wf = Tpf - T; Tpf = T;
        facc += wf; fdep = fmaf(wf, pt, fdep);
        fr01 = fma2((v2f){wf, wf}, pc01, fr01);
        fr2 = fmaf(wf, pc2, fr2);
        if (samp) { jf += 1.0f; }
        else {
            lo = hi; hi = Snext * inv_total;
            bin0 = bin1; bin1 = fminf(bin1 + W, TMAX); binw = bin1 - bin0;
            ++i; Snext = s_cdf[min(i, 63)][col];
        }
        pt = tm; ps = F.sig; pc01 = F.c01; pc2 = F.c2;
    }
    {   // tail: A composites element 63 (dist = t64 - t63); B composites 127 (FAR)
        float dnm = hi - lo; dnm = (dnm < EPS_W_C) ? 1.0f : dnm;
        const float u = jf * INV63;
        const float ts = fmaf((u - lo) * rcp_fast(dnm), binw, bin0);
        const bool samp = (jf < 63.5f) && ((i >= 64) || (u < hi));
        const float tm = samp ? ts : bin1;          // A: t_64; B: unused
        const float sig_safe = softplus2_safe(fmaf(pt, A1.x, A0.x));
        const float ps_e = isB ? sig_safe : ps;
        const float dist = isB ? FAR_DIST : (tm - pt);
        Sf = fmaf(ps_e, dist, Sf);
        const float T = exp2_f(-Sf);
        const float wf = Tpf - T;
        facc += wf; fdep = fmaf(wf, pt, fdep);
        fr01 = fma2((v2f){wf, wf}, pc01, fr01);
        fr2 = fmaf(wf, pc2, fr2);
    }
    {   // fine combine on A: global = A + exp2(-Sf_A) * B_local
        const float TFA = exp2_f(-Sf);              // A: T at element-64 boundary
        const float bfacc = shfx1(facc), bfdep = shfx1(fdep), bfr2 = shfx1(fr2);
        const float bf0 = shfx1(fr01.x), bf1 = shfx1(fr01.y);
        if (!isB) {
            const float ga = fmaf(TFA, bfacc, facc);
            const float gd = fmaf(TFA, bfdep, fdep);
            const float g0 = fmaf(TFA, bf0, fr01.x);
            const float g1 = fmaf(TFA, bf1, fr01.y);
            const float g2 = fmaf(TFA, bfr2, fr2);
            const float bg = 1.0f - ga;
            out_frgb[ray * 3 + 0] = g0 + bg;
            out_frgb[ray * 3 + 1] = g1 + bg;
            out_frgb[ray * 3 + 2] = g2 + bg;
            out_fdep[ray] = gd;
            out_facc[ray] = ga;
        }
    }
}

extern "C" void kernel_launch(void* const* d_in, const int* in_sizes, int n_in,
                              void* d_out, int out_size, void* d_ws, size_t ws_size,
                              hipStream_t stream) {
    const float* ro = (const float*)d_in[0];
    const float* rd = (const float*)d_in[1];
    // d_in[2] exposure_values, d_in[5] appearance_ids: unused by reference
    const float* Wd = (const float*)d_in[3];
    const float* Wc = (const float*)d_in[4];
    float* out = (float*)d_out;

    const int N = in_sizes[0] / 3;
    const int grid = (2 * N + 255) / 256;
    volrender_tpr2<<<grid, 256, 0, stream>>>(ro, rd, Wd, Wc, out, N);
}